// Round 2
// baseline (329.570 us; speedup 1.0000x reference)
//
#include <hip/hip_runtime.h>

// ROI max pooling, restructured for wave-uniform control flow + coalesced access.
// features: [1,512,64,64] fp32  proposals: [2000,4] fp32  out: [2000,512,7,7] fp32
//
// Pass 1: transpose features -> ft[h][w][c] (8 MB in d_ws), both sides coalesced.
// Pass 2: block = proposal; thread t owns channels 2t,2t+1. Bin bounds are
//         wave-uniform (SGPR via readfirstlane) -> zero divergence; loads are
//         float2 coalesced across lanes; 49 accumulators statically indexed.

#define NCH   512
#define FH    64
#define FW    64
#define NPROP 2000
#define ROI   7
#define OUT_PER_PROP (NCH * ROI * ROI)   // 25088

__global__ __launch_bounds__(256) void transpose_kernel(
    const float* __restrict__ f,   // [512][64][64]
    float* __restrict__ ft)        // [64][64][512]
{
    __shared__ float tile[64][65];         // [c_local][w], pad -> conflict-free
    const int h  = blockIdx.x;             // 0..63
    const int c0 = blockIdx.y * 64;        // 0..448
    const int tw = threadIdx.x & 63;
    const int tg = threadIdx.x >> 6;       // 0..3
#pragma unroll
    for (int r = 0; r < 16; ++r) {
        const int cl = r * 4 + tg;
        tile[cl][tw] = f[(size_t)(c0 + cl) * (FH * FW) + h * FW + tw];  // lane=w coalesced
    }
    __syncthreads();
#pragma unroll
    for (int r = 0; r < 16; ++r) {
        const int wl = r * 4 + tg;
        ft[((size_t)(h * FW + wl)) * NCH + c0 + tw] = tile[tw][wl];     // lane=c coalesced
    }
}

__global__ __launch_bounds__(256) void roipool_kernel(
    const float* __restrict__ ft,      // [64][64][512]
    const float* __restrict__ props,   // [2000][4]
    float* __restrict__ out)           // [2000][512][7][7]
{
    const int n = blockIdx.x;
    const float NEG = -3.402823466e+38f;

    __shared__ int s_hs[ROI], s_he[ROI], s_ws[ROI], s_we[ROI];
    if (threadIdx.x < ROI) {
        const int i = threadIdx.x;
        const int x1 = (int)floorf(props[n * 4 + 0] * 0.0625f);
        const int y1 = (int)floorf(props[n * 4 + 1] * 0.0625f);
        const int x2 = (int)floorf(props[n * 4 + 2] * 0.0625f);
        const int y2 = (int)floorf(props[n * 4 + 3] * 0.0625f);
        const int Lh = y2 - y1;
        const int Lw = x2 - x1;
        s_hs[i] = max(y1 + (i * Lh) / ROI, 0);
        s_he[i] = min(y1 + ((i + 1) * Lh + (ROI - 1)) / ROI, FH);
        s_ws[i] = max(x1 + (i * Lw) / ROI, 0);
        s_we[i] = min(x1 + ((i + 1) * Lw + (ROI - 1)) / ROI, FW);
    }
    __syncthreads();

    // hoist bin bounds to SGPRs -> scalar (uniform) loop control, fewer VGPRs
    int hs[ROI], he[ROI], ws[ROI], we[ROI];
#pragma unroll
    for (int i = 0; i < ROI; ++i) {
        hs[i] = __builtin_amdgcn_readfirstlane(s_hs[i]);
        he[i] = __builtin_amdgcn_readfirstlane(s_he[i]);
        ws[i] = __builtin_amdgcn_readfirstlane(s_ws[i]);
        we[i] = __builtin_amdgcn_readfirstlane(s_we[i]);
    }

    const float2* __restrict__ ft2 = (const float2*)ft;  // index (h*64+w)*256 + tid
    float a0[ROI * ROI], a1[ROI * ROI];                  // channels 2t and 2t+1

#pragma unroll
    for (int bi = 0; bi < ROI; ++bi) {
        float c0[ROI], c1[ROI];
#pragma unroll
        for (int j = 0; j < ROI; ++j) { c0[j] = NEG; c1[j] = NEG; }

        for (int h = hs[bi]; h < he[bi]; ++h) {
            const float2* __restrict__ rowp = ft2 + (size_t)h * (FW * 256) + threadIdx.x;
#pragma unroll
            for (int j = 0; j < ROI; ++j) {
                for (int w = ws[j]; w < we[j]; ++w) {       // uniform trip count
                    const float2 v = rowp[(size_t)w * 256]; // coalesced 512B/wave
                    c0[j] = fmaxf(c0[j], v.x);
                    c1[j] = fmaxf(c1[j], v.y);
                }
            }
        }
#pragma unroll
        for (int j = 0; j < ROI; ++j) { a0[bi * ROI + j] = c0[j]; a1[bi * ROI + j] = c1[j]; }
    }

    // store: thread owns rows c=2t and c+1 -> two contiguous 49-float spans
    const int c = threadIdx.x * 2;
    float* outn = out + (size_t)n * OUT_PER_PROP;

    float* r0 = outn + (size_t)c * 49;        // byte offset 392*t -> 8B aligned
#pragma unroll
    for (int k = 0; k < 48; k += 2)
        *(float2*)(r0 + k) = make_float2(a0[k], a0[k + 1]);
    r0[48] = a0[48];

    float* r1 = outn + (size_t)(c + 1) * 49;  // base ≡ 4 (mod 8): pair from k=1
    r1[0] = a1[0];
#pragma unroll
    for (int k = 1; k < 48; k += 2)
        *(float2*)(r1 + k) = make_float2(a1[k], a1[k + 1]);
}

extern "C" void kernel_launch(void* const* d_in, const int* in_sizes, int n_in,
                              void* d_out, int out_size, void* d_ws, size_t ws_size,
                              hipStream_t stream) {
    const float* feats = (const float*)d_in[0];   // [1,512,64,64]
    const float* props = (const float*)d_in[1];   // [2000,4]
    float* out = (float*)d_out;
    float* ft  = (float*)d_ws;                    // 64*64*512 floats = 8 MB

    transpose_kernel<<<dim3(FH, NCH / 64), 256, 0, stream>>>(feats, ft);
    roipool_kernel<<<dim3(NPROP), 256, 0, stream>>>(ft, props, out);
}

// Round 3
// 173.292 us; speedup vs baseline: 1.9018x; 1.9018x over previous
//
#include <hip/hip_runtime.h>

// ROI max pooling via w-direction sparse-table (RMQ) + uniform control flow.
// features: [1,512,64,64] fp32  proposals: [2000,4] fp32  out: [2000,512,7,7] fp32
//
// Prep (1 launch): transpose f[c][h][w] -> T0[h][w][c] AND build w-range-max
// tables T1 (len-2) and T2 (len-4) from the LDS tile. 3 x 8 MB slots in d_ws.
// Query: block = proposal, thread = 2 channels (float2). Per w-bin the max is
// fmax of exactly 2 table lookups (bin len <= 5, kw <= 2), so the 7-bin loop
// is fully unrolled -> 14 independent coalesced loads per h-iteration (MLP).
// Bin bounds are wave-uniform (readfirstlane -> SGPR); zero divergence.

#define NCH   512
#define FH    64
#define FW    64
#define NPROP 2000
#define ROI   7
#define OUT_PER_PROP (NCH * ROI * ROI)       // 25088
#define SLOT  (FH * FW * NCH)                // floats per table = 2M (8 MB)

__global__ __launch_bounds__(256) void prep_kernel(
    const float* __restrict__ f,   // [512][64][64]
    float* __restrict__ ws,        // T0 | T1 | T2, each [64][64][512]
    int nlevels)
{
    __shared__ float tile[64][65];           // [c_local][w]
    const int h  = blockIdx.x;
    const int c0 = blockIdx.y * 64;
    const int tw = threadIdx.x & 63;
    const int tg = threadIdx.x >> 6;
#pragma unroll
    for (int r = 0; r < 16; ++r) {
        const int cl = r * 4 + tg;
        tile[cl][tw] = f[(size_t)(c0 + cl) * (FH * FW) + h * FW + tw];
    }
    __syncthreads();
    float* __restrict__ T0 = ws;
    float* __restrict__ T1 = ws + SLOT;
    float* __restrict__ T2 = ws + 2 * SLOT;
#pragma unroll
    for (int r = 0; r < 16; ++r) {
        const int wl = r * 4 + tg;
        const float v0 = tile[tw][wl];
        const float v1 = tile[tw][min(wl + 1, 63)];
        const float v2 = tile[tw][min(wl + 2, 63)];
        const float v3 = tile[tw][min(wl + 3, 63)];
        const float m1 = fmaxf(v0, v1);                 // max over [w, w+2)
        const float m2 = fmaxf(m1, fmaxf(v2, v3));      // max over [w, w+4)
        const size_t o = ((size_t)(h * FW + wl)) * NCH + c0 + tw;
        T0[o] = v0;
        if (nlevels >= 3) { T1[o] = m1; T2[o] = m2; }   // uniform branch
    }
}

__device__ __forceinline__ void compute_bins(
    const float* __restrict__ props, int n,
    int* s_hs, int* s_he, int* s_ws, int* s_we)
{
    if (threadIdx.x < ROI) {
        const int i = threadIdx.x;
        const int x1 = (int)floorf(props[n * 4 + 0] * 0.0625f);
        const int y1 = (int)floorf(props[n * 4 + 1] * 0.0625f);
        const int x2 = (int)floorf(props[n * 4 + 2] * 0.0625f);
        const int y2 = (int)floorf(props[n * 4 + 3] * 0.0625f);
        const int Lh = y2 - y1;
        const int Lw = x2 - x1;
        s_hs[i] = max(y1 + (i * Lh) / ROI, 0);
        s_he[i] = min(y1 + ((i + 1) * Lh + (ROI - 1)) / ROI, FH);
        s_ws[i] = max(x1 + (i * Lw) / ROI, 0);
        s_we[i] = min(x1 + ((i + 1) * Lw + (ROI - 1)) / ROI, FW);
    }
}

__device__ __forceinline__ void store_rows(
    float* __restrict__ outn, const float* a0, const float* a1)
{
    const int c = threadIdx.x * 2;
    float* r0 = outn + (size_t)c * 49;        // 8B aligned (392*t)
#pragma unroll
    for (int k = 0; k < 48; k += 2)
        *(float2*)(r0 + k) = make_float2(a0[k], a0[k + 1]);
    r0[48] = a0[48];
    float* r1 = outn + (size_t)(c + 1) * 49;  // base ≡ 4 (mod 8)
    r1[0] = a1[0];
#pragma unroll
    for (int k = 1; k < 48; k += 2)
        *(float2*)(r1 + k) = make_float2(a1[k], a1[k + 1]);
}

__global__ __launch_bounds__(256) void roipool_rmq_kernel(
    const float* __restrict__ tabs,    // 3 slots [64][64][512]
    const float* __restrict__ props,
    float* __restrict__ out)
{
    const int n = blockIdx.x;
    const float NEG = -3.402823466e+38f;

    __shared__ int s_hs[ROI], s_he[ROI], s_ws[ROI], s_we[ROI];
    compute_bins(props, n, s_hs, s_he, s_ws, s_we);
    __syncthreads();

    int hs[ROI], he[ROI];
    int o1[ROI], o2[ROI];   // float2-offsets into tabs for the 2 lookups per w-bin
#pragma unroll
    for (int j = 0; j < ROI; ++j) {
        hs[j] = __builtin_amdgcn_readfirstlane(s_hs[j]);
        he[j] = __builtin_amdgcn_readfirstlane(s_he[j]);
        const int wsj = __builtin_amdgcn_readfirstlane(s_ws[j]);
        const int wej = __builtin_amdgcn_readfirstlane(s_we[j]);
        const int len = wej - wsj;                  // 1..5
        const int kw  = (len >= 4) ? 2 : ((len >= 2) ? 1 : 0);
        const int w2  = wej - (1 << kw);
        const int slot2 = kw * (SLOT / 2);          // float2 units
        o1[j] = slot2 + wsj * (NCH / 2);
        o2[j] = slot2 + w2  * (NCH / 2);
    }

    const float2* __restrict__ t2 = (const float2*)tabs;
    const int lane = threadIdx.x;

    float a0[ROI * ROI], a1[ROI * ROI];
#pragma unroll
    for (int bi = 0; bi < ROI; ++bi) {
        float c0j[ROI], c1j[ROI];
#pragma unroll
        for (int j = 0; j < ROI; ++j) { c0j[j] = NEG; c1j[j] = NEG; }

        for (int h = hs[bi]; h < he[bi]; ++h) {
            const int ro = h * (FW * NCH / 2) + lane;
#pragma unroll
            for (int j = 0; j < ROI; ++j) {         // 14 independent loads
                const float2 u = t2[(size_t)(o1[j] + ro)];
                const float2 v = t2[(size_t)(o2[j] + ro)];
                c0j[j] = fmaxf(c0j[j], fmaxf(u.x, v.x));
                c1j[j] = fmaxf(c1j[j], fmaxf(u.y, v.y));
            }
        }
#pragma unroll
        for (int j = 0; j < ROI; ++j) { a0[bi * ROI + j] = c0j[j]; a1[bi * ROI + j] = c1j[j]; }
    }

    store_rows(out + (size_t)n * OUT_PER_PROP, a0, a1);
}

// Fallback (ws_size < 24 MB): level-0 only, runtime w-loop (round-2 behavior).
__global__ __launch_bounds__(256) void roipool_kernel(
    const float* __restrict__ ft,      // [64][64][512]
    const float* __restrict__ props,
    float* __restrict__ out)
{
    const int n = blockIdx.x;
    const float NEG = -3.402823466e+38f;

    __shared__ int s_hs[ROI], s_he[ROI], s_ws[ROI], s_we[ROI];
    compute_bins(props, n, s_hs, s_he, s_ws, s_we);
    __syncthreads();

    int hs[ROI], he[ROI], wsx[ROI], wex[ROI];
#pragma unroll
    for (int i = 0; i < ROI; ++i) {
        hs[i]  = __builtin_amdgcn_readfirstlane(s_hs[i]);
        he[i]  = __builtin_amdgcn_readfirstlane(s_he[i]);
        wsx[i] = __builtin_amdgcn_readfirstlane(s_ws[i]);
        wex[i] = __builtin_amdgcn_readfirstlane(s_we[i]);
    }

    const float2* __restrict__ ft2 = (const float2*)ft;
    float a0[ROI * ROI], a1[ROI * ROI];

#pragma unroll
    for (int bi = 0; bi < ROI; ++bi) {
        float c0j[ROI], c1j[ROI];
#pragma unroll
        for (int j = 0; j < ROI; ++j) { c0j[j] = NEG; c1j[j] = NEG; }
        for (int h = hs[bi]; h < he[bi]; ++h) {
            const float2* __restrict__ rowp = ft2 + (size_t)h * (FW * 256) + threadIdx.x;
#pragma unroll
            for (int j = 0; j < ROI; ++j) {
                for (int w = wsx[j]; w < wex[j]; ++w) {
                    const float2 v = rowp[(size_t)w * 256];
                    c0j[j] = fmaxf(c0j[j], v.x);
                    c1j[j] = fmaxf(c1j[j], v.y);
                }
            }
        }
#pragma unroll
        for (int j = 0; j < ROI; ++j) { a0[bi * ROI + j] = c0j[j]; a1[bi * ROI + j] = c1j[j]; }
    }
    store_rows(out + (size_t)n * OUT_PER_PROP, a0, a1);
}

extern "C" void kernel_launch(void* const* d_in, const int* in_sizes, int n_in,
                              void* d_out, int out_size, void* d_ws, size_t ws_size,
                              hipStream_t stream) {
    const float* feats = (const float*)d_in[0];
    const float* props = (const float*)d_in[1];
    float* out = (float*)d_out;
    float* ws  = (float*)d_ws;

    const bool rmq = ws_size >= (size_t)3 * SLOT * sizeof(float);   // 24 MB
    prep_kernel<<<dim3(FH, NCH / 64), 256, 0, stream>>>(feats, ws, rmq ? 3 : 1);
    if (rmq)
        roipool_rmq_kernel<<<dim3(NPROP), 256, 0, stream>>>(ws, props, out);
    else
        roipool_kernel<<<dim3(NPROP), 256, 0, stream>>>(ws, props, out);
}

// Round 4
// 131.000 us; speedup vs baseline: 2.5158x; 1.3228x over previous
//
#include <hip/hip_runtime.h>

// ROI max pooling via w-direction sparse-table (RMQ), uniform control flow,
// and line-covering coalesced output stores (LDS-transposed, chunked).
// features: [1,512,64,64] fp32  proposals: [2000,4] fp32  out: [2000,512,7,7] fp32
//
// Round-4 fix: round 3's per-thread 49-float row stores were 8B/lane at 196B
// stride -> every 64B line assembled from 8 partial stores -> ~198 MB of
// write-allocate FETCH. Now each block stages 128ch x 49 outputs in LDS
// (linear image of the output span) and stores 25088 contiguous bytes with
// consecutive-lane float2 stores: every line fully covered by one wave instr.

#define NCH   512
#define FH    64
#define FW    64
#define NPROP 2000
#define ROI   7
#define OUT_PER_PROP (NCH * ROI * ROI)       // 25088
#define SLOT  (FH * FW * NCH)                // floats per table = 2M (8 MB)

__global__ __launch_bounds__(256) void prep_kernel(
    const float* __restrict__ f,   // [512][64][64]
    float* __restrict__ ws,        // T0 | T1 | T2, each [64][64][512]
    int nlevels)
{
    __shared__ float tile[64][65];           // [c_local][w]
    const int h  = blockIdx.x;
    const int c0 = blockIdx.y * 64;
    const int tw = threadIdx.x & 63;
    const int tg = threadIdx.x >> 6;
#pragma unroll
    for (int r = 0; r < 16; ++r) {
        const int cl = r * 4 + tg;
        tile[cl][tw] = f[(size_t)(c0 + cl) * (FH * FW) + h * FW + tw];
    }
    __syncthreads();
    float* __restrict__ T0 = ws;
    float* __restrict__ T1 = ws + SLOT;
    float* __restrict__ T2 = ws + 2 * SLOT;
#pragma unroll
    for (int r = 0; r < 16; ++r) {
        const int wl = r * 4 + tg;
        const float v0 = tile[tw][wl];
        const float v1 = tile[tw][min(wl + 1, 63)];
        const float v2 = tile[tw][min(wl + 2, 63)];
        const float v3 = tile[tw][min(wl + 3, 63)];
        const float m1 = fmaxf(v0, v1);                 // max over [w, w+2)
        const float m2 = fmaxf(m1, fmaxf(v2, v3));      // max over [w, w+4)
        const size_t o = ((size_t)(h * FW + wl)) * NCH + c0 + tw;
        T0[o] = v0;
        if (nlevels >= 3) { T1[o] = m1; T2[o] = m2; }
    }
}

__device__ __forceinline__ void compute_bins(
    const float* __restrict__ props, int n,
    int* s_hs, int* s_he, int* s_ws, int* s_we)
{
    if (threadIdx.x < ROI) {
        const int i = threadIdx.x;
        const int x1 = (int)floorf(props[n * 4 + 0] * 0.0625f);
        const int y1 = (int)floorf(props[n * 4 + 1] * 0.0625f);
        const int x2 = (int)floorf(props[n * 4 + 2] * 0.0625f);
        const int y2 = (int)floorf(props[n * 4 + 3] * 0.0625f);
        const int Lh = y2 - y1;
        const int Lw = x2 - x1;
        s_hs[i] = max(y1 + (i * Lh) / ROI, 0);
        s_he[i] = min(y1 + ((i + 1) * Lh + (ROI - 1)) / ROI, FH);
        s_ws[i] = max(x1 + (i * Lw) / ROI, 0);
        s_we[i] = min(x1 + ((i + 1) * Lw + (ROI - 1)) / ROI, FW);
    }
}

__global__ __launch_bounds__(256) void roipool_rmq_kernel(
    const float* __restrict__ tabs,    // 3 slots [64][64][512]
    const float* __restrict__ props,
    float* __restrict__ out)
{
    const int n = blockIdx.x;
    const float NEG = -3.402823466e+38f;

    __shared__ int s_hs[ROI], s_he[ROI], s_ws[ROI], s_we[ROI];
    __shared__ float s_stage[128 * 49];          // 25088 B: one 128-channel chunk
    compute_bins(props, n, s_hs, s_he, s_ws, s_we);
    __syncthreads();

    int hs[ROI], he[ROI];
    int o1[ROI], o2[ROI];   // float2-offsets into tabs for the 2 lookups per w-bin
#pragma unroll
    for (int j = 0; j < ROI; ++j) {
        hs[j] = __builtin_amdgcn_readfirstlane(s_hs[j]);
        he[j] = __builtin_amdgcn_readfirstlane(s_he[j]);
        const int wsj = __builtin_amdgcn_readfirstlane(s_ws[j]);
        const int wej = __builtin_amdgcn_readfirstlane(s_we[j]);
        const int len = wej - wsj;                  // 1..5
        const int kw  = (len >= 4) ? 2 : ((len >= 2) ? 1 : 0);
        const int w2  = wej - (1 << kw);
        const int slot2 = kw * (SLOT / 2);          // float2 units
        o1[j] = slot2 + wsj * (NCH / 2);
        o2[j] = slot2 + w2  * (NCH / 2);
    }

    const float2* __restrict__ t2 = (const float2*)tabs;
    const int lane = threadIdx.x;

    float a0[ROI * ROI], a1[ROI * ROI];             // channels 2t, 2t+1
#pragma unroll
    for (int bi = 0; bi < ROI; ++bi) {
        float c0j[ROI], c1j[ROI];
#pragma unroll
        for (int j = 0; j < ROI; ++j) { c0j[j] = NEG; c1j[j] = NEG; }

        for (int h = hs[bi]; h < he[bi]; ++h) {
            const int ro = h * (FW * NCH / 2) + lane;
#pragma unroll
            for (int j = 0; j < ROI; ++j) {         // 14 independent loads
                const float2 u = t2[(size_t)(o1[j] + ro)];
                const float2 v = t2[(size_t)(o2[j] + ro)];
                c0j[j] = fmaxf(c0j[j], fmaxf(u.x, v.x));
                c1j[j] = fmaxf(c1j[j], fmaxf(u.y, v.y));
            }
        }
#pragma unroll
        for (int j = 0; j < ROI; ++j) { a0[bi * ROI + j] = c0j[j]; a1[bi * ROI + j] = c1j[j]; }
    }

    // ---- chunked transpose-store: 4 chunks of 128 channels ----
    // Chunk q (channels 128q..128q+127) is owned by wave q (threads 64q..64q+63,
    // thread t owns c = 2t, 2t+1). The wave dumps its 98 floats at the exact
    // linear output offsets; then all threads store the contiguous 25088 B span
    // with consecutive float2s (full 64B-line coverage -> no write-allocate).
    float2* outn2 = (float2*)(out + (size_t)n * OUT_PER_PROP);
    float2* lds2  = (float2*)s_stage;
    const int wq = threadIdx.x >> 6;
    const int wl = threadIdx.x & 63;

    for (int q = 0; q < 4; ++q) {
        if (wq == q) {
            float2* dst = lds2 + wl * 49;            // floats [98*wl, 98*wl+98)
#pragma unroll
            for (int k = 0; k < 24; ++k) dst[k] = make_float2(a0[2 * k], a0[2 * k + 1]);
            dst[24] = make_float2(a0[48], a1[0]);
#pragma unroll
            for (int k = 0; k < 24; ++k) dst[25 + k] = make_float2(a1[2 * k + 1], a1[2 * k + 2]);
        }
        __syncthreads();
        for (int i = threadIdx.x; i < 3136; i += 256)   // 3136 float2 = 25088 B
            outn2[q * 3136 + i] = lds2[i];
        __syncthreads();
    }
}

// Fallback (ws_size < 24 MB): level-0 only, runtime w-loop (round-2 behavior).
__global__ __launch_bounds__(256) void roipool_kernel(
    const float* __restrict__ ft,      // [64][64][512]
    const float* __restrict__ props,
    float* __restrict__ out)
{
    const int n = blockIdx.x;
    const float NEG = -3.402823466e+38f;

    __shared__ int s_hs[ROI], s_he[ROI], s_ws[ROI], s_we[ROI];
    __shared__ float s_stage[128 * 49];
    compute_bins(props, n, s_hs, s_he, s_ws, s_we);
    __syncthreads();

    int hs[ROI], he[ROI], wsx[ROI], wex[ROI];
#pragma unroll
    for (int i = 0; i < ROI; ++i) {
        hs[i]  = __builtin_amdgcn_readfirstlane(s_hs[i]);
        he[i]  = __builtin_amdgcn_readfirstlane(s_he[i]);
        wsx[i] = __builtin_amdgcn_readfirstlane(s_ws[i]);
        wex[i] = __builtin_amdgcn_readfirstlane(s_we[i]);
    }

    const float2* __restrict__ ft2 = (const float2*)ft;
    float a0[ROI * ROI], a1[ROI * ROI];

#pragma unroll
    for (int bi = 0; bi < ROI; ++bi) {
        float c0j[ROI], c1j[ROI];
#pragma unroll
        for (int j = 0; j < ROI; ++j) { c0j[j] = NEG; c1j[j] = NEG; }
        for (int h = hs[bi]; h < he[bi]; ++h) {
            const float2* __restrict__ rowp = ft2 + (size_t)h * (FW * 256) + threadIdx.x;
#pragma unroll
            for (int j = 0; j < ROI; ++j) {
                for (int w = wsx[j]; w < wex[j]; ++w) {
                    const float2 v = rowp[(size_t)w * 256];
                    c0j[j] = fmaxf(c0j[j], v.x);
                    c1j[j] = fmaxf(c1j[j], v.y);
                }
            }
        }
#pragma unroll
        for (int j = 0; j < ROI; ++j) { a0[bi * ROI + j] = c0j[j]; a1[bi * ROI + j] = c1j[j]; }
    }

    float2* outn2 = (float2*)(out + (size_t)n * OUT_PER_PROP);
    float2* lds2  = (float2*)s_stage;
    const int wq = threadIdx.x >> 6;
    const int wl = threadIdx.x & 63;
    for (int q = 0; q < 4; ++q) {
        if (wq == q) {
            float2* dst = lds2 + wl * 49;
#pragma unroll
            for (int k = 0; k < 24; ++k) dst[k] = make_float2(a0[2 * k], a0[2 * k + 1]);
            dst[24] = make_float2(a0[48], a1[0]);
#pragma unroll
            for (int k = 0; k < 24; ++k) dst[25 + k] = make_float2(a1[2 * k + 1], a1[2 * k + 2]);
        }
        __syncthreads();
        for (int i = threadIdx.x; i < 3136; i += 256)
            outn2[q * 3136 + i] = lds2[i];
        __syncthreads();
    }
}

extern "C" void kernel_launch(void* const* d_in, const int* in_sizes, int n_in,
                              void* d_out, int out_size, void* d_ws, size_t ws_size,
                              hipStream_t stream) {
    const float* feats = (const float*)d_in[0];
    const float* props = (const float*)d_in[1];
    float* out = (float*)d_out;
    float* ws  = (float*)d_ws;

    const bool rmq = ws_size >= (size_t)3 * SLOT * sizeof(float);   // 24 MB
    prep_kernel<<<dim3(FH, NCH / 64), 256, 0, stream>>>(feats, ws, rmq ? 3 : 1);
    if (rmq)
        roipool_rmq_kernel<<<dim3(NPROP), 256, 0, stream>>>(ws, props, out);
    else
        roipool_kernel<<<dim3(NPROP), 256, 0, stream>>>(ws, props, out);
}

// Round 5
// 89.164 us; speedup vs baseline: 3.6962x; 1.4692x over previous
//
#include <hip/hip_runtime.h>

// ROI max pooling, round 5: channel-chunked tables pinned per-XCD-L2.
// features: [1,512,64,64] fp32  proposals: [2000,4] fp32  out: [2000,512,7,7] fp32
//
// Tables per 128-channel chunk: T0 (raw, [h][w][128c]) + T1 (len-2 w-max).
// 2 levels x 2 MB = 4 MB per chunk -> fits one XCD L2. Block b handles
// (proposal b>>2, chunk b&3); with round-robin XCD dispatch chunk q only
// runs on XCDs {q, q+4}, so each L2 caches exactly its chunk's tables.
// Any w-bin (len 1..5) = max of <=3 overlapping lookups (len5 rare: 3rd load
// on a block-uniform slow path). Output stores are nontemporal so the 200 MB
// write stream doesn't evict table lines from L2.

#define NCH   512
#define FH    64
#define FW    64
#define NPROP 2000
#define ROI   7
#define OUT_PER_PROP (NCH * ROI * ROI)       // 25088
#define NCHUNK 4
#define CCH    128                            // channels per chunk
#define LVL_F  (FH * FW * CCH)                // 524288 floats per level (2 MB)
#define CHUNK_F (2 * LVL_F)                   // T0+T1 per chunk (4 MB)
#define L1_F2  (LVL_F / 2)                    // level-1 offset in float2 units
#define TAB_BYTES ((size_t)NCHUNK * CHUNK_F * 4)   // 16 MB

__global__ __launch_bounds__(256) void prep2_kernel(
    const float* __restrict__ f,   // [512][64][64]
    float* __restrict__ ws)        // 4 chunks x { T0 | T1 }, each [64][64][128]
{
    __shared__ float tile[64][65];           // [c_local][w]
    const int h  = blockIdx.x;
    const int c0 = blockIdx.y * 64;
    const int tw = threadIdx.x & 63;
    const int tg = threadIdx.x >> 6;
#pragma unroll
    for (int r = 0; r < 16; ++r) {
        const int cl = r * 4 + tg;
        tile[cl][tw] = f[(size_t)(c0 + cl) * (FH * FW) + h * FW + tw];
    }
    __syncthreads();
    const int q     = c0 >> 7;               // chunk
    const int cbase = c0 & 64;               // 0 or 64 within chunk
    float* __restrict__ T = ws + (size_t)q * CHUNK_F;
#pragma unroll
    for (int r = 0; r < 16; ++r) {
        const int wl = r * 4 + tg;
        const float v0 = tile[tw][wl];
        const float v1 = fmaxf(v0, tile[tw][min(wl + 1, 63)]);  // max over [w,w+2)
        const int sp = h * FW + wl;
        T[(size_t)sp * CCH + cbase + tw]          = v0;
        T[LVL_F + (size_t)sp * CCH + cbase + tw]  = v1;
    }
}

__device__ __forceinline__ void compute_bins(
    const float* __restrict__ props, int n,
    int* s_hs, int* s_he, int* s_ws, int* s_we)
{
    if (threadIdx.x < ROI) {
        const int i = threadIdx.x;
        const int x1 = (int)floorf(props[n * 4 + 0] * 0.0625f);
        const int y1 = (int)floorf(props[n * 4 + 1] * 0.0625f);
        const int x2 = (int)floorf(props[n * 4 + 2] * 0.0625f);
        const int y2 = (int)floorf(props[n * 4 + 3] * 0.0625f);
        const int Lh = y2 - y1;
        const int Lw = x2 - x1;
        s_hs[i] = max(y1 + (i * Lh) / ROI, 0);
        s_he[i] = min(y1 + ((i + 1) * Lh + (ROI - 1)) / ROI, FH);
        s_ws[i] = max(x1 + (i * Lw) / ROI, 0);
        s_we[i] = min(x1 + ((i + 1) * Lw + (ROI - 1)) / ROI, FW);
    }
}

// Accumulate max over this block's chunk. bi indexed via LDS (runtime bi would
// push a local array to scratch -- rule #20); bounds hoisted to SGPR.
template<bool THREE>
__device__ __forceinline__ void do_accum(
    const float2* __restrict__ t2, const int c2, const int wq,
    const int* __restrict__ s_hs, const int* __restrict__ s_he,
    const int o1[ROI], const int o2[ROI], const int o3[ROI],
    float acc0[2][ROI], float acc1[2][ROI])
{
    const float NEG = -3.402823466e+38f;
#pragma unroll
    for (int r = 0; r < 2; ++r) {
        const int bi = wq + 4 * r;
        if (bi >= ROI) break;                    // uniform (wave 3, r==1)
        const int h0 = __builtin_amdgcn_readfirstlane(s_hs[bi]);
        const int h1 = __builtin_amdgcn_readfirstlane(s_he[bi]);
        float m0[ROI], m1[ROI];
#pragma unroll
        for (int j = 0; j < ROI; ++j) { m0[j] = NEG; m1[j] = NEG; }
        for (int h = h0; h < h1; ++h) {
            const float2* __restrict__ row = t2 + (size_t)h * (FW * CCH / 2) + c2;
#pragma unroll
            for (int j = 0; j < ROI; ++j) {      // <=21 independent loads/iter
                const float2 u = row[o1[j]];
                const float2 v = row[o2[j]];
                float x0 = fmaxf(u.x, v.x);
                float x1 = fmaxf(u.y, v.y);
                if (THREE) {
                    const float2 w3 = row[o3[j]];
                    x0 = fmaxf(x0, w3.x);
                    x1 = fmaxf(x1, w3.y);
                }
                m0[j] = fmaxf(m0[j], x0);
                m1[j] = fmaxf(m1[j], x1);
            }
        }
#pragma unroll
        for (int j = 0; j < ROI; ++j) { acc0[r][j] = m0[j]; acc1[r][j] = m1[j]; }
    }
}

__global__ __launch_bounds__(256) void roipool_l2_kernel(
    const float* __restrict__ tabs,
    const float* __restrict__ props,
    float* __restrict__ out)
{
    const int b = blockIdx.x;
    const int q = b & 3;          // chunk -> XCDs {q, q+4} under round-robin
    const int n = b >> 2;

    __shared__ int s_hs[ROI], s_he[ROI], s_ws[ROI], s_we[ROI];
    __shared__ float s_stage[CCH * 49];      // 25088 B
    compute_bins(props, n, s_hs, s_he, s_ws, s_we);
    __syncthreads();

    // per-w-bin lookup offsets (float2 units, uniform -> SGPR):
    // len1: T0@ws ; len2: T1@ws ; len>=3: + T1@(we-2) ; len5: + T1@(ws+2)
    int o1[ROI], o2[ROI], o3[ROI];
    bool any5 = false;
#pragma unroll
    for (int j = 0; j < ROI; ++j) {
        const int wsj = __builtin_amdgcn_readfirstlane(s_ws[j]);
        const int wej = __builtin_amdgcn_readfirstlane(s_we[j]);
        const int len = wej - wsj;                 // 1..5
        o1[j] = ((len == 1) ? 0 : L1_F2) + wsj * (CCH / 2);
        o2[j] = (len >= 3) ? (L1_F2 + (wej - 2) * (CCH / 2)) : o1[j];
        o3[j] = (len == 5) ? (L1_F2 + (wsj + 2) * (CCH / 2)) : o1[j];
        any5 = any5 || (len == 5);
    }

    const float2* __restrict__ t2 = (const float2*)tabs + (size_t)q * (CHUNK_F / 2);
    const int c2 = threadIdx.x & 63;   // float2 channel within chunk
    const int wq = threadIdx.x >> 6;   // wave -> bi in {wq, wq+4}

    float acc0[2][ROI], acc1[2][ROI];
    if (any5) do_accum<true >(t2, c2, wq, s_hs, s_he, o1, o2, o3, acc0, acc1);
    else      do_accum<false>(t2, c2, wq, s_hs, s_he, o1, o2, o3, acc0, acc1);

    // stage chunk's 128x49 outputs in LDS at exact linear offsets, then store
    // the contiguous 25088 B span with nontemporal float2 (full-line, no L2 pollution)
#pragma unroll
    for (int r = 0; r < 2; ++r) {
        const int bi = wq + 4 * r;
        if (bi >= ROI) break;
#pragma unroll
        for (int j = 0; j < ROI; ++j) {
            s_stage[(2 * c2)     * 49 + bi * 7 + j] = acc0[r][j];
            s_stage[(2 * c2 + 1) * 49 + bi * 7 + j] = acc1[r][j];
        }
    }
    __syncthreads();

    double* __restrict__ dsto = (double*)(out + (size_t)n * OUT_PER_PROP + q * (CCH * 49));
    const double* __restrict__ srco = (const double*)s_stage;
    for (int i = threadIdx.x; i < (CCH * 49 / 2); i += 256)   // 3136 float2
        __builtin_nontemporal_store(srco[i], dsto + i);
}

// Fallback if ws too small: direct divergent kernel (round-1 style; correct).
__global__ __launch_bounds__(256) void roipool_direct_kernel(
    const float* __restrict__ feats,
    const float* __restrict__ props,
    float* __restrict__ out)
{
    const int n = blockIdx.x;
    __shared__ int s_hs[ROI], s_he[ROI], s_ws[ROI], s_we[ROI];
    compute_bins(props, n, s_hs, s_he, s_ws, s_we);
    __syncthreads();
    const float NEG = -3.402823466e+38f;
    const int base = blockIdx.y * (256 * ROI);
    float* outn = out + (size_t)n * OUT_PER_PROP;
#pragma unroll
    for (int k = 0; k < ROI; ++k) {
        const int idx = base + k * 256 + threadIdx.x;
        const int c   = idx / (ROI * ROI);
        const int bin = idx - c * (ROI * ROI);
        const int bi  = bin / ROI;
        const int bj  = bin - bi * ROI;
        float acc = NEG;
        for (int h = s_hs[bi]; h < s_he[bi]; ++h)
            for (int w = s_ws[bj]; w < s_we[bj]; ++w)
                acc = fmaxf(acc, feats[(size_t)c * (FH * FW) + h * FW + w]);
        outn[idx] = acc;
    }
}

extern "C" void kernel_launch(void* const* d_in, const int* in_sizes, int n_in,
                              void* d_out, int out_size, void* d_ws, size_t ws_size,
                              hipStream_t stream) {
    const float* feats = (const float*)d_in[0];
    const float* props = (const float*)d_in[1];
    float* out = (float*)d_out;
    float* ws  = (float*)d_ws;

    if (ws_size >= TAB_BYTES) {
        prep2_kernel<<<dim3(FH, NCH / 64), 256, 0, stream>>>(feats, ws);
        roipool_l2_kernel<<<dim3(NPROP * NCHUNK), 256, 0, stream>>>(ws, props, out);
    } else {
        roipool_direct_kernel<<<dim3(NPROP, ROI * 2), 256, 0, stream>>>(feats, props, out);
    }
}

// Round 6
// 78.021 us; speedup vs baseline: 4.2241x; 1.1428x over previous
//
#include <hip/hip_runtime.h>

// ROI max pooling, round 6: 2D RMQ tables (h AND w), chunk-per-XCD-L2, no
// runtime loops in the query at all.
// features: [1,512,64,64] fp32  proposals: [2000,4] fp32  out: [2000,512,7,7] fp32
//
// Tables per 64-channel chunk: M[kh][kw][h][w][64c], kh,kw in {0,1} (len-1 and
// len-2 windows per dim). 4 tables x 1 MB = 4 MB = one XCD L2. Block b ->
// (proposal b>>3, chunk b&7); round-robin dispatch pins chunk q to XCD q.
// Any bin (lens 1..5) = max of (2..3)x(2..3) overlapping lookups, all
// statically addressed -> 28 independent loads per thread, zero inner loops.
// Output via LDS stage + contiguous nontemporal float2 (full-line, no L2 alloc).

#define NCH   512
#define FH    64
#define FW    64
#define NPROP 2000
#define ROI   7
#define OUT_PER_PROP (NCH * ROI * ROI)       // 25088
#define NCHUNK 8
#define CCH    64                            // channels per chunk
#define TABF   (FH * FW * CCH)               // 262144 floats = 1 MB per table
#define CHUNK_F (4 * TABF)                   // M00|M01|M10|M11
#define TAB_BYTES ((size_t)NCHUNK * CHUNK_F * 4)   // 32 MB
#define ROWF2  (FW * CCH / 2)                // 2048 float2 per (table,h) row

__global__ __launch_bounds__(256) void prep2d_kernel(
    const float* __restrict__ f,   // [512][64][64]
    float* __restrict__ ws)
{
    __shared__ float tA[64][65];             // row h   [c_local][w]
    __shared__ float tB[64][65];             // row h+1 (clamped)
    const int b  = blockIdx.x;
    const int q  = b & 7;                    // chunk -> XCD q (round-robin)
    const int h  = b >> 3;
    const int h2 = min(h + 1, FH - 1);
    const int c0 = q * CCH;
    const int tw = threadIdx.x & 63;
    const int tg = threadIdx.x >> 6;
#pragma unroll
    for (int r = 0; r < 16; ++r) {
        const int cl = r * 4 + tg;
        tA[cl][tw] = f[(size_t)(c0 + cl) * (FH * FW) + h  * FW + tw];
        tB[cl][tw] = f[(size_t)(c0 + cl) * (FH * FW) + h2 * FW + tw];
    }
    __syncthreads();
    float* __restrict__ T = ws + (size_t)q * CHUNK_F + h * (FW * CCH);
#pragma unroll
    for (int r = 0; r < 16; ++r) {
        const int wl = r * 4 + tg;
        const int w1 = min(wl + 1, FW - 1);
        const float a0 = tA[tw][wl], a1 = tA[tw][w1];
        const float b0 = tB[tw][wl], b1 = tB[tw][w1];
        const float m01 = fmaxf(a0, a1);                 // 1h x 2w
        const float m10 = fmaxf(a0, b0);                 // 2h x 1w
        const float m11 = fmaxf(m01, fmaxf(b0, b1));     // 2h x 2w
        const int o = wl * CCH + tw;
        T[o]            = a0;
        T[TABF + o]     = m01;
        T[2 * TABF + o] = m10;
        T[3 * TABF + o] = m11;
    }
}

__device__ __forceinline__ void compute_bins(
    const float* __restrict__ props, int n,
    int* s_hs, int* s_he, int* s_ws, int* s_we)
{
    if (threadIdx.x < ROI) {
        const int i = threadIdx.x;
        const int x1 = (int)floorf(props[n * 4 + 0] * 0.0625f);
        const int y1 = (int)floorf(props[n * 4 + 1] * 0.0625f);
        const int x2 = (int)floorf(props[n * 4 + 2] * 0.0625f);
        const int y2 = (int)floorf(props[n * 4 + 3] * 0.0625f);
        const int Lh = y2 - y1;
        const int Lw = x2 - x1;
        s_hs[i] = max(y1 + (i * Lh) / ROI, 0);
        s_he[i] = min(y1 + ((i + 1) * Lh + (ROI - 1)) / ROI, FH);
        s_ws[i] = max(x1 + (i * Lw) / ROI, 0);
        s_we[i] = min(x1 + ((i + 1) * Lw + (ROI - 1)) / ROI, FW);
    }
}

// All loads statically addressed; H3/W3 add the rare 3rd lookup (len==5 dims).
template<bool H3, bool W3>
__device__ __forceinline__ void accum2d(
    const float2* __restrict__ t2,
    int baseA, int baseB, int baseC,                       // per-thread f2 offsets
    const int sA[ROI], const int sB[ROI], const int sC[ROI],  // per-j uniform offsets
    float m0[ROI], float m1[ROI])
{
#pragma unroll
    for (int j = 0; j < ROI; ++j) {
        const float2 uAA = t2[(size_t)(baseA + sA[j])];
        const float2 uAB = t2[(size_t)(baseA + sB[j])];
        const float2 uBA = t2[(size_t)(baseB + sA[j])];
        const float2 uBB = t2[(size_t)(baseB + sB[j])];
        float x0 = fmaxf(fmaxf(uAA.x, uAB.x), fmaxf(uBA.x, uBB.x));
        float x1 = fmaxf(fmaxf(uAA.y, uAB.y), fmaxf(uBA.y, uBB.y));
        if (W3) {
            const float2 uAC = t2[(size_t)(baseA + sC[j])];
            const float2 uBC = t2[(size_t)(baseB + sC[j])];
            x0 = fmaxf(x0, fmaxf(uAC.x, uBC.x));
            x1 = fmaxf(x1, fmaxf(uAC.y, uBC.y));
        }
        if (H3) {
            const float2 uCA = t2[(size_t)(baseC + sA[j])];
            const float2 uCB = t2[(size_t)(baseC + sB[j])];
            x0 = fmaxf(x0, fmaxf(uCA.x, uCB.x));
            x1 = fmaxf(x1, fmaxf(uCA.y, uCB.y));
            if (W3) {
                const float2 uCC = t2[(size_t)(baseC + sC[j])];
                x0 = fmaxf(x0, uCC.x);
                x1 = fmaxf(x1, uCC.y);
            }
        }
        m0[j] = x0;
        m1[j] = x1;
    }
}

__global__ __launch_bounds__(256) void roipool_2d_kernel(
    const float* __restrict__ tabs,
    const float* __restrict__ props,
    float* __restrict__ out)
{
    const int b = blockIdx.x;
    const int q = b & 7;           // chunk -> XCD q under round-robin dispatch
    const int n = b >> 3;

    __shared__ int s_hs[ROI], s_he[ROI], s_ws[ROI], s_we[ROI];
    __shared__ float s_stage[CCH * 49];      // 12544 B
    compute_bins(props, n, s_hs, s_he, s_ws, s_we);
    __syncthreads();

    // per-w-bin lookup offsets (block-uniform -> SGPR), in float2 units:
    // s = kw*(TABF/2) + w*(CCH/2)
    int sA[ROI], sB[ROI], sC[ROI];
    bool w5 = false, h5 = false;
#pragma unroll
    for (int j = 0; j < ROI; ++j) {
        const int wsj = __builtin_amdgcn_readfirstlane(s_ws[j]);
        const int wej = __builtin_amdgcn_readfirstlane(s_we[j]);
        const int len = wej - wsj;                        // 1..5
        const int kwo = (len >= 2) ? (TABF / 2) : 0;
        const int wB  = (len >= 3) ? (wej - 2) : wsj;
        const int wC  = (len == 5) ? (wsj + 2) : wsj;
        sA[j] = kwo + wsj * (CCH / 2);
        sB[j] = kwo + wB  * (CCH / 2);
        sC[j] = kwo + wC  * (CCH / 2);
        w5 = w5 || (len == 5);
        const int hl = __builtin_amdgcn_readfirstlane(s_he[j]) -
                       __builtin_amdgcn_readfirstlane(s_hs[j]);
        h5 = h5 || (hl == 5);
    }

    // per-thread: slot -> h-bin; h params read from LDS (dynamic bi -> LDS, not
    // a local array: rule #20), kept in VGPRs.
    const int slot = threadIdx.x >> 5;       // 0..7
    const int bi   = min(slot, 6);           // slot 7 duplicates bi 6 (no store)
    const int c2   = threadIdx.x & 31;       // float2 channel within chunk
    const int hsb  = s_hs[bi];
    const int heb  = s_he[bi];
    const int hlen = heb - hsb;
    const int khoff = (hlen >= 2) ? TABF : 0;            // kh*2 tables, f2 units
    const int hB   = (hlen >= 3) ? (heb - 2) : hsb;
    const int hC   = (hlen == 5) ? (hsb + 2) : hsb;

    const float2* __restrict__ t2 = (const float2*)tabs + (size_t)q * (CHUNK_F / 2);
    const int baseA = khoff + hsb * ROWF2 + c2;
    const int baseB = khoff + hB  * ROWF2 + c2;
    const int baseC = khoff + hC  * ROWF2 + c2;

    float m0[ROI], m1[ROI];
    if (h5) {
        if (w5) accum2d<true,  true >(t2, baseA, baseB, baseC, sA, sB, sC, m0, m1);
        else    accum2d<true,  false>(t2, baseA, baseB, baseC, sA, sB, sC, m0, m1);
    } else {
        if (w5) accum2d<false, true >(t2, baseA, baseB, baseC, sA, sB, sC, m0, m1);
        else    accum2d<false, false>(t2, baseA, baseB, baseC, sA, sB, sC, m0, m1);
    }

    if (slot < 7) {
#pragma unroll
        for (int j = 0; j < ROI; ++j) {
            s_stage[(2 * c2)     * 49 + bi * 7 + j] = m0[j];
            s_stage[(2 * c2 + 1) * 49 + bi * 7 + j] = m1[j];
        }
    }
    __syncthreads();

    // contiguous 12544 B span for (n, chunk q): full-line nontemporal stores
    double* __restrict__ dsto = (double*)(out + (size_t)n * OUT_PER_PROP + q * (CCH * 49));
    const double* __restrict__ srco = (const double*)s_stage;
    for (int i = threadIdx.x; i < (CCH * 49 / 2); i += 256)   // 1568 float2
        __builtin_nontemporal_store(srco[i], dsto + i);
}

// Fallback if ws too small: direct divergent kernel (correct, slower).
__global__ __launch_bounds__(256) void roipool_direct_kernel(
    const float* __restrict__ feats,
    const float* __restrict__ props,
    float* __restrict__ out)
{
    const int n = blockIdx.x;
    __shared__ int s_hs[ROI], s_he[ROI], s_ws[ROI], s_we[ROI];
    compute_bins(props, n, s_hs, s_he, s_ws, s_we);
    __syncthreads();
    const float NEG = -3.402823466e+38f;
    const int base = blockIdx.y * (256 * ROI);
    float* outn = out + (size_t)n * OUT_PER_PROP;
#pragma unroll
    for (int k = 0; k < ROI; ++k) {
        const int idx = base + k * 256 + threadIdx.x;
        const int c   = idx / (ROI * ROI);
        const int bin = idx - c * (ROI * ROI);
        const int bi  = bin / ROI;
        const int bj  = bin - bi * ROI;
        float acc = NEG;
        for (int h = s_hs[bi]; h < s_he[bi]; ++h)
            for (int w = s_ws[bj]; w < s_we[bj]; ++w)
                acc = fmaxf(acc, feats[(size_t)c * (FH * FW) + h * FW + w]);
        outn[idx] = acc;
    }
}

extern "C" void kernel_launch(void* const* d_in, const int* in_sizes, int n_in,
                              void* d_out, int out_size, void* d_ws, size_t ws_size,
                              hipStream_t stream) {
    const float* feats = (const float*)d_in[0];
    const float* props = (const float*)d_in[1];
    float* out = (float*)d_out;
    float* ws  = (float*)d_ws;

    if (ws_size >= TAB_BYTES) {
        prep2d_kernel<<<dim3(FH * NCHUNK), 256, 0, stream>>>(feats, ws);
        roipool_2d_kernel<<<dim3(NPROP * NCHUNK), 256, 0, stream>>>(ws, props, out);
    } else {
        roipool_direct_kernel<<<dim3(NPROP, ROI * 2), 256, 0, stream>>>(feats, props, out);
    }
}